// Round 2
// baseline (748.098 us; speedup 1.0000x reference)
//
#include <hip/hip_runtime.h>
#include <hip/hip_bf16.h>
#include <math.h>

// Sizes (static per problem)
#define T_LEN 4096
#define R_REG 49
#define D_DIM 512
#define N_SEG 256
#define N_CLASS 106
#define N_CAT 18

// d_out element offsets (fp32 elements), return order: keysteps, cats, alphas_sp, alphas_ks
#define OFF_KS 0
#define OFF_CATS (N_CLASS * N_SEG)                 // 27136
#define OFF_ASP (OFF_CATS + N_CAT)                 // 27154
#define OFF_AKS (OFF_ASP + T_LEN * R_REG)          // 227858

__device__ __forceinline__ float wave_reduce_add(float p) {
    p += __shfl_xor(p, 1);
    p += __shfl_xor(p, 2);
    p += __shfl_xor(p, 4);
    p += __shfl_xor(p, 8);
    p += __shfl_xor(p, 16);
    p += __shfl_xor(p, 32);
    return p;
}

// ---------------- K1: spatial attention + fbar, one block per t ----------------
// 512 threads: thread owns d = tid. Keeps all 49 rows' elements in registers.
__global__ __launch_bounds__(512, 4) void k1_spatial(
    const float* __restrict__ feat, const float* __restrict__ att_w,
    const float* __restrict__ att_b, float* __restrict__ alphas_out,
    float* __restrict__ fbar) {
    const int t = blockIdx.x;
    const int tid = threadIdx.x;
    const int lane = tid & 63;
    const int wave = tid >> 6;

    __shared__ float lds_p[R_REG * 9];   // stride 9 to dodge bank conflicts
    __shared__ float lds_alpha[64];

    const float* fp = feat + (size_t)t * R_REG * D_DIM + tid;
    float fr[R_REG];
#pragma unroll
    for (int r = 0; r < R_REG; ++r) fr[r] = fp[(size_t)r * D_DIM];

    const float w = att_w[tid];
#pragma unroll
    for (int r = 0; r < R_REG; ++r) {
        float p = fr[r] * w;
        p = wave_reduce_add(p);
        if (lane == 0) lds_p[r * 9 + wave] = p;
    }
    __syncthreads();

    if (wave == 0) {
        float s = -INFINITY;
        if (lane < R_REG) {
            s = att_b[0];
#pragma unroll
            for (int j = 0; j < 8; ++j) s += lds_p[lane * 9 + j];
        }
        float m = s;
        for (int off = 32; off; off >>= 1) m = fmaxf(m, __shfl_xor(m, off));
        float e = (lane < R_REG) ? expf(s - m) : 0.f;
        float sum = e;
        for (int off = 32; off; off >>= 1) sum += __shfl_xor(sum, off);
        float a = e / sum;
        if (lane < R_REG) {
            lds_alpha[lane] = a;
            alphas_out[t * R_REG + lane] = a;
        }
    }
    __syncthreads();

    float acc = 0.f;
#pragma unroll
    for (int r = 0; r < R_REG; ++r) acc += lds_alpha[r] * fr[r];
    fbar[(size_t)t * D_DIM + tid] = acc;
}

// ---------------- K2: segment mean pool, one block per segment ----------------
__global__ void k2_segmean(const int* __restrict__ ids, const float* __restrict__ fbar,
                           float* __restrict__ x_sd, float* __restrict__ x_ds) {
    const int s = blockIdx.x;
    const int tid = threadIdx.x;  // 256
    __shared__ int seg_range[2];
    if (tid == 0) {
        int lo = 0, hi = T_LEN;
        while (lo < hi) { int mid = (lo + hi) >> 1; if (ids[mid] < s) lo = mid + 1; else hi = mid; }
        seg_range[0] = lo;
        hi = T_LEN;
        while (lo < hi) { int mid = (lo + hi) >> 1; if (ids[mid] < s + 1) lo = mid + 1; else hi = mid; }
        seg_range[1] = lo;
    }
    __syncthreads();
    const int start = seg_range[0], end = seg_range[1];
    const float inv = (end > start) ? 1.f / (float)(end - start) : 0.f;
    float a0 = 0.f, a1 = 0.f;
    for (int ti = start; ti < end; ++ti) {
        a0 += fbar[(size_t)ti * D_DIM + tid];
        a1 += fbar[(size_t)ti * D_DIM + tid + 256];
    }
    a0 *= inv; a1 *= inv;
    x_sd[s * D_DIM + tid] = a0;
    x_sd[s * D_DIM + tid + 256] = a1;
    x_ds[tid * N_SEG + s] = a0;
    x_ds[(tid + 256) * N_SEG + s] = a1;
}

// ---------------- K3: conv1d 512->512 k=3 SAME + ReLU ----------------
// 256 blocks, 512 threads. Block computes 2 output channels over all s.
// Threads: s = tid&255, g = tid>>8 splits the i range in half.
__global__ __launch_bounds__(512) void k3_conv(
    const float* __restrict__ x_ds, const float* __restrict__ w1,
    const float* __restrict__ b1, float* __restrict__ h) {
    const int o0 = blockIdx.x * 2;
    const int o1 = o0 + 1;
    const int tid = threadIdx.x;
    const int s = tid & 255;
    const int g = tid >> 8;

    __shared__ float xl[32][256];
    __shared__ float red[2][256];

    float acc0 = 0.f, acc1 = 0.f;
    for (int c = 0; c < 16; ++c) {
        __syncthreads();
        const float4* src = (const float4*)(x_ds + (size_t)c * 32 * 256);
#pragma unroll
        for (int jj = 0; jj < 4; ++jj) {
            int flat = jj * 512 + tid;           // float4 index, 0..2047
            int row = flat >> 6, col4 = flat & 63;
            ((float4*)&xl[row][col4 * 4])[0] = src[row * 64 + col4];
        }
        __syncthreads();
        const int ibase = g * 16;
#pragma unroll
        for (int il = 0; il < 16; ++il) {
            const int i = ibase + il;
            const float xm = xl[i][s];
            const float xa = (s == 0) ? 0.f : xl[i][s - 1];
            const float xb = (s == 255) ? 0.f : xl[i][s + 1];
            const int gi = c * 32 + i;
            const float* wp0 = w1 + ((size_t)o0 * D_DIM + gi) * 3;  // block-uniform -> scalar loads
            const float* wp1 = w1 + ((size_t)o1 * D_DIM + gi) * 3;
            acc0 += xa * wp0[0] + xm * wp0[1] + xb * wp0[2];
            acc1 += xa * wp1[0] + xm * wp1[1] + xb * wp1[2];
        }
    }
    if (g == 1) { red[0][s] = acc0; red[1][s] = acc1; }
    __syncthreads();
    if (g == 0) {
        acc0 += red[0][s] + b1[o0];
        acc1 += red[1][s] + b1[o1];
        h[o0 * N_SEG + s] = fmaxf(acc0, 0.f);
        h[o1 * N_SEG + s] = fmaxf(acc1, 0.f);
    }
}

// ---------------- K4: keysteps = w2 @ h + b2 (writes fp32 directly to d_out) ----------------
__global__ void k4_keysteps(const float* __restrict__ h, const float* __restrict__ w2,
                            const float* __restrict__ b2, float* __restrict__ ks_out) {
    const int m = blockIdx.x;
    const int s = threadIdx.x;  // 256
    float acc = b2[m];
    const float* wp = w2 + (size_t)m * D_DIM;  // block-uniform -> scalar loads
    for (int i = 0; i < D_DIM; ++i) acc += h[i * N_SEG + s] * wp[i];
    ks_out[m * N_SEG + s] = acc;
}

// ---------------- K5a: per-s softmax stats over classes ----------------
__global__ void k5a_stats(const float* __restrict__ ks, float* __restrict__ mx,
                          float* __restrict__ rden) {
    const int s = threadIdx.x;  // 256, grid 1
    float m = -INFINITY;
    for (int mm = 0; mm < N_CLASS; ++mm) m = fmaxf(m, ks[mm * N_SEG + s]);
    float sum = 0.f;
    for (int mm = 0; mm < N_CLASS; ++mm) sum += expf(ks[mm * N_SEG + s] - m);
    mx[s] = m;
    rden[s] = 1.f / sum;
}

// ---------------- K5b: f_keysteps[m,d] = sum_s x[s,d] * att[m,s] ----------------
__global__ void k5b_fks(const float* __restrict__ ks, const float* __restrict__ mx,
                        const float* __restrict__ rden, const float* __restrict__ x_sd,
                        float* __restrict__ fk) {
    const int m = blockIdx.x;
    const int tid = threadIdx.x;  // 256
    __shared__ float att[N_SEG];
    att[tid] = expf(ks[m * N_SEG + tid] - mx[tid]) * rden[tid];
    __syncthreads();
    float a0 = 0.f, a1 = 0.f;
    for (int s = 0; s < N_SEG; ++s) {
        const float a = att[s];
        a0 += x_sd[s * D_DIM + tid] * a;
        a1 += x_sd[s * D_DIM + tid + 256] * a;
    }
    fk[m * D_DIM + tid] = a0;
    fk[m * D_DIM + tid + 256] = a1;
}

// ---------------- K6: keystep attention + final classifier ----------------
__global__ void k6_final(const float* __restrict__ fk, const float* __restrict__ att2_w,
                         const float* __restrict__ att2_b, const float* __restrict__ cls_w,
                         const float* __restrict__ cls_b, float* __restrict__ cats,
                         float* __restrict__ aks_out) {
    const int tid = threadIdx.x;  // 256
    const int lane = tid & 63;
    const int wave = tid >> 6;
    __shared__ float s2[128];
    __shared__ float alpha[128];
    __shared__ float fv[D_DIM];

    float aw[8];
#pragma unroll
    for (int j = 0; j < 8; ++j) aw[j] = att2_w[lane * 8 + j];

    for (int m = wave; m < N_CLASS; m += 4) {
        const float* fp = fk + (size_t)m * D_DIM + lane * 8;
        float p = 0.f;
#pragma unroll
        for (int j = 0; j < 8; ++j) p += fp[j] * aw[j];
        p = wave_reduce_add(p);
        if (lane == 0) s2[m] = p + att2_b[0];
    }
    __syncthreads();

    if (wave == 0) {
        float v0 = (lane < N_CLASS) ? s2[lane] : -INFINITY;
        float v1 = (lane + 64 < N_CLASS) ? s2[lane + 64] : -INFINITY;
        float m = fmaxf(v0, v1);
        for (int off = 32; off; off >>= 1) m = fmaxf(m, __shfl_xor(m, off));
        float e0 = (lane < N_CLASS) ? expf(v0 - m) : 0.f;
        float e1 = (lane + 64 < N_CLASS) ? expf(v1 - m) : 0.f;
        float sum = e0 + e1;
        for (int off = 32; off; off >>= 1) sum += __shfl_xor(sum, off);
        const float r = 1.f / sum;
        if (lane < N_CLASS) { alpha[lane] = e0 * r; aks_out[lane] = e0 * r; }
        if (lane + 64 < N_CLASS) { alpha[lane + 64] = e1 * r; aks_out[lane + 64] = e1 * r; }
    }
    __syncthreads();

    float a0 = 0.f, a1 = 0.f;
    for (int m = 0; m < N_CLASS; ++m) {
        const float a = alpha[m];
        a0 += fk[(size_t)m * D_DIM + tid] * a;
        a1 += fk[(size_t)m * D_DIM + tid + 256] * a;
    }
    fv[tid] = a0;
    fv[tid + 256] = a1;
    __syncthreads();

    if (tid < N_CAT) {
        float acc = cls_b[tid];
        for (int d = 0; d < D_DIM; ++d) acc += fv[d] * cls_w[d * N_CAT + tid];
        cats[tid] = acc;
    }
}

extern "C" void kernel_launch(void* const* d_in, const int* in_sizes, int n_in,
                              void* d_out, int out_size, void* d_ws, size_t ws_size,
                              hipStream_t stream) {
    const float* feature = (const float*)d_in[0];
    const int* seg_ids   = (const int*)d_in[1];
    const float* att_w   = (const float*)d_in[2];
    const float* att_b   = (const float*)d_in[3];
    const float* att2_w  = (const float*)d_in[4];
    const float* att2_b  = (const float*)d_in[5];
    const float* w1      = (const float*)d_in[6];
    const float* b1      = (const float*)d_in[7];
    const float* w2      = (const float*)d_in[8];
    const float* b2      = (const float*)d_in[9];
    const float* cls_w   = (const float*)d_in[10];
    const float* cls_b   = (const float*)d_in[11];

    float* out = (float*)d_out;
    float* out_ks  = out + OFF_KS;
    float* out_cat = out + OFF_CATS;
    float* out_asp = out + OFF_ASP;
    float* out_aks = out + OFF_AKS;

    float* ws = (float*)d_ws;
    float* fbar = ws;                                  // 4096*512 = 2097152
    float* x_sd = fbar + (size_t)T_LEN * D_DIM;        // 256*512 = 131072
    float* x_ds = x_sd + N_SEG * D_DIM;                // 131072
    float* h    = x_ds + N_SEG * D_DIM;                // 131072
    float* mx   = h + D_DIM * N_SEG;                   // 256
    float* rden = mx + N_SEG;                          // 256
    float* fk   = rden + N_SEG;                        // 106*512 = 54272

    k1_spatial<<<T_LEN, 512, 0, stream>>>(feature, att_w, att_b, out_asp, fbar);
    k2_segmean<<<N_SEG, 256, 0, stream>>>(seg_ids, fbar, x_sd, x_ds);
    k3_conv<<<D_DIM / 2, 512, 0, stream>>>(x_ds, w1, b1, h);
    k4_keysteps<<<N_CLASS, 256, 0, stream>>>(h, w2, b2, out_ks);
    k5a_stats<<<1, 256, 0, stream>>>(out_ks, mx, rden);
    k5b_fks<<<N_CLASS, 256, 0, stream>>>(out_ks, mx, rden, x_sd, fk);
    k6_final<<<1, 256, 0, stream>>>(fk, att2_w, att2_b, cls_w, cls_b, out_cat, out_aks);
}